// Round 8
// baseline (847.407 us; speedup 1.0000x reference)
//
#include <hip/hip_runtime.h>
#include <hip/hip_bf16.h>
#include <math.h>

#define Bn 4
#define Nn 2048
#define FIN 128
#define Hh 4
#define HIDn 32
#define En 4
#define ZS 32            // logical i-splits in K2
#define RPT (Nn / ZS)    // 64 rows per block

// MEASUREMENT ROUND: K2 runs 2x and K4 runs 8x via redundant grid halves
// (remapped blockIdx; identical values re-stored -> idempotent, benign
// same-value races). Pushes both kernels past the ~160us harness-fill
// visibility threshold so their counter rows appear in the top-5.
// Accounting vs the 475.6us round-2 baseline:
//   K2_true = row/2, K4_true = row/8, residual = 475.6 - K2_true - K4_true.

typedef __bf16 bf16x8 __attribute__((ext_vector_type(8)));
typedef __bf16 bf16x2 __attribute__((ext_vector_type(2)));
typedef float  f32x4  __attribute__((ext_vector_type(4)));
typedef float  f32x4v __attribute__((ext_vector_type(4)));
typedef int    i32x2v __attribute__((ext_vector_type(2)));

// K1: ht = h @ W  (B,N,128); emit htT bf16 [b][h][hid][n], s_i/s_j fp32 [b][h][n]
__global__ __launch_bounds__(256) void k1_proj(const float* __restrict__ h,
    const float* __restrict__ W, const float* __restrict__ a,
    __bf16* __restrict__ htT, float* __restrict__ s_i, float* __restrict__ s_j)
{
    __shared__ float hl[16][FIN];
    const int b  = blockIdx.y;
    const int n0 = blockIdx.x * 16;
    const int t  = threadIdx.x;
    for (int k = t; k < 16 * FIN; k += 256) {
        int r = k >> 7, f = k & 127;
        hl[r][f] = h[((size_t)(b * Nn + n0 + r)) * FIN + f];
    }
    __syncthreads();
    const int d   = t & 127;
    const int ng  = t >> 7;
    const int hh  = d >> 5;
    const int hid = d & 31;
    float acc[8];
#pragma unroll
    for (int r = 0; r < 8; r++) acc[r] = 0.f;
    for (int f = 0; f < FIN; f++) {
        float wv = W[f * 128 + d];
#pragma unroll
        for (int r = 0; r < 8; r++) acc[r] = fmaf(hl[ng * 8 + r][f], wv, acc[r]);
    }
    const float ai = a[hh * 68 + hid];
    const float aj = a[hh * 68 + 32 + hid];
#pragma unroll
    for (int r = 0; r < 8; r++) {
        float vi = acc[r] * ai;
        float vj = acc[r] * aj;
#pragma unroll
        for (int m = 16; m >= 1; m >>= 1) {
            vi += __shfl_xor(vi, m, 64);
            vj += __shfl_xor(vj, m, 64);
        }
        if (hid == 0) {
            int n = n0 + ng * 8 + r;
            s_i[(b * Hh + hh) * Nn + n] = vi;
            s_j[(b * Hh + hh) * Nn + n] = vj;
        }
    }
    bf16x8 pack;
#pragma unroll
    for (int r = 0; r < 8; r++) pack[r] = (__bf16)acc[r];
    *(bf16x8*)(htT + ((size_t)((b * Hh + hh) * HIDn + hid)) * Nn + n0 + ng * 8) = pack;
}

// K2: P[b][h][i][j] = adj ? exp(s_i + s_j + edge.a_e) : 0  (bf16, unnormalized)
//     Dpart[b][h][z][j] = partial column sums over this block's i-range
//     PROBE: gridDim.z = 2*ZS; z = blockIdx.z & (ZS-1) -> work done twice.
__global__ __launch_bounds__(256) void k2_pexp(const float* __restrict__ edge,
    const int* __restrict__ adj, const float* __restrict__ a,
    const float* __restrict__ s_i, const float* __restrict__ s_j,
    __bf16* __restrict__ P, float* __restrict__ Dpart)
{
    __shared__ float si_l[4][RPT];
    const int b  = blockIdx.y;
    const int z  = blockIdx.z & (ZS - 1);   // PROBE remap (0..63 -> 0..31)
    const int i0 = z * RPT;
    const int t  = threadIdx.x;
    const int j0 = blockIdx.x * 512 + t * 2;
    si_l[t >> 6][t & 63] = s_i[(b * Hh + (t >> 6)) * Nn + i0 + (t & 63)];
    float ae[4][4];
#pragma unroll
    for (int hh = 0; hh < 4; hh++)
#pragma unroll
        for (int e = 0; e < 4; e++) ae[hh][e] = a[hh * 68 + 64 + e];
    float sj0[4], sj1[4];
#pragma unroll
    for (int hh = 0; hh < 4; hh++) {
        sj0[hh] = s_j[(b * Hh + hh) * Nn + j0];
        sj1[hh] = s_j[(b * Hh + hh) * Nn + j0 + 1];
    }
    __syncthreads();
    float D0[4] = {0.f, 0.f, 0.f, 0.f};
    float D1[4] = {0.f, 0.f, 0.f, 0.f};
    const float* ep = edge + ((size_t)(b * Nn + i0)) * Nn * En + (size_t)j0 * En;
    const int*   ap = adj  + ((size_t)(b * Nn + i0)) * Nn + j0;
    __bf16*      pp = P    + ((size_t)(b * Hh) * Nn + i0) * Nn + j0;
    const size_t PS = (size_t)Nn * Nn;   // head-plane stride
#pragma unroll 2
    for (int ii = 0; ii < RPT; ii++) {
        const f32x4v e0 = __builtin_nontemporal_load((const f32x4v*)ep);
        const f32x4v e1 = __builtin_nontemporal_load(((const f32x4v*)ep) + 1);
        const i32x2v av = __builtin_nontemporal_load((const i32x2v*)ap);
        ep += (size_t)Nn * En;
        ap += Nn;
#pragma unroll
        for (int hh = 0; hh < 4; hh++) {
            const float base = si_l[hh][ii];
            float d0 = base + sj0[hh];
            float d1 = base + sj1[hh];
            d0 = fmaf(e0[0], ae[hh][0], d0); d0 = fmaf(e0[1], ae[hh][1], d0);
            d0 = fmaf(e0[2], ae[hh][2], d0); d0 = fmaf(e0[3], ae[hh][3], d0);
            d1 = fmaf(e1[0], ae[hh][0], d1); d1 = fmaf(e1[1], ae[hh][1], d1);
            d1 = fmaf(e1[2], ae[hh][2], d1); d1 = fmaf(e1[3], ae[hh][3], d1);
            const float p0 = (av[0] > 0) ? __expf(d0) : 0.f;
            const float p1 = (av[1] > 0) ? __expf(d1) : 0.f;
            D0[hh] += p0;
            D1[hh] += p1;
            bf16x2 pv;
            pv[0] = (__bf16)p0;
            pv[1] = (__bf16)p1;
            *(bf16x2*)(pp + hh * PS) = pv;
        }
        pp += Nn;
    }
#pragma unroll
    for (int hh = 0; hh < 4; hh++) {
        float2 dv;
        dv.x = D0[hh];
        dv.y = D1[hh];
        *(float2*)(Dpart + ((size_t)((b * Hh + hh) * ZS + z)) * Nn + j0) = dv;
    }
}

// K3a: rcpD[bh][j] = 1 / sum_z Dpart[bh][z][j]   (tiny, 128 KB out)
__global__ __launch_bounds__(256) void k3a_rcp(const float* __restrict__ Dpart,
    float* __restrict__ rcpD)
{
    const int idx = blockIdx.x * 256 + threadIdx.x;   // bh*Nn + j
    const int bh  = idx >> 11;
    const int j   = idx & (Nn - 1);
    float S = 0.f;
#pragma unroll
    for (int z = 0; z < ZS; z++)
        S += Dpart[((size_t)(bh * ZS + z)) * Nn + j];
    rcpD[idx] = (S > 0.f) ? 1.f / S : 0.f;
}

// K3b: htD[bh][d][j] = htT[bh][d][j] * rcpD[bh][j]  (bf16x8 vectorized)
__global__ __launch_bounds__(256) void k3b_scale(const float* __restrict__ rcpD,
    const __bf16* __restrict__ htT, __bf16* __restrict__ htD)
{
    const int idx = blockIdx.x * 256 + threadIdx.x;   // [bh][d][n/8]
    const int oct = idx & 255;
    const int d   = (idx >> 8) & 31;
    const int bh  = idx >> 13;
    const int n0  = oct * 8;
    const size_t o = ((size_t)(bh * HIDn + d)) * Nn + n0;
    const bf16x8 v = *(const bf16x8*)(htT + o);
    const float4 r0 = *(const float4*)(rcpD + bh * Nn + n0);
    const float4 r1 = *(const float4*)(rcpD + bh * Nn + n0 + 4);
    bf16x8 w;
    w[0] = (__bf16)((float)v[0] * r0.x);
    w[1] = (__bf16)((float)v[1] * r0.y);
    w[2] = (__bf16)((float)v[2] * r0.z);
    w[3] = (__bf16)((float)v[3] * r0.w);
    w[4] = (__bf16)((float)v[4] * r1.x);
    w[5] = (__bf16)((float)v[5] * r1.y);
    w[6] = (__bf16)((float)v[6] * r1.z);
    w[7] = (__bf16)((float)v[7] * r1.w);
    *(bf16x8*)(htD + o) = w;
}

// K4: out[b][i][h*32+d] = sum_j P[bh][i][j] * htD[bh][d][j]   (bf16 MFMA GEMM)
//     PROBE: gridDim.x = 8*(Nn/64); x = blockIdx.x & 31 -> work done 8x.
__global__ __launch_bounds__(256) void k4_gemm(const __bf16* __restrict__ P,
    const __bf16* __restrict__ htD, float* __restrict__ out)
{
    const int bh   = blockIdx.y;
    const int t    = threadIdx.x;
    const int w    = t >> 6;
    const int lane = t & 63;
    const int quad = lane >> 4;
    const int lrow = lane & 15;
    const int x    = blockIdx.x & 31;       // PROBE remap (0..255 -> 0..31)
    const int i0   = x * 64 + w * 16;

    const __bf16* Arow = P   + (size_t)bh * Nn * Nn + (size_t)(i0 + lrow) * Nn + quad * 8;
    const __bf16* B0   = htD + (size_t)bh * HIDn * Nn + (size_t)lrow * Nn + quad * 8;
    const __bf16* B1   = B0 + (size_t)16 * Nn;

    f32x4 acc0 = {0.f, 0.f, 0.f, 0.f};
    f32x4 acc1 = {0.f, 0.f, 0.f, 0.f};
#pragma unroll 4
    for (int k0 = 0; k0 < Nn; k0 += 32) {
        bf16x8 af = *(const bf16x8*)(Arow + k0);
        bf16x8 b0 = *(const bf16x8*)(B0 + k0);
        bf16x8 b1 = *(const bf16x8*)(B1 + k0);
        acc0 = __builtin_amdgcn_mfma_f32_16x16x32_bf16(af, b0, acc0, 0, 0, 0);
        acc1 = __builtin_amdgcn_mfma_f32_16x16x32_bf16(af, b1, acc1, 0, 0, 0);
    }
    const int b = bh >> 2, hh = bh & 3;
#pragma unroll
    for (int r = 0; r < 4; r++) {
        const int i = i0 + quad * 4 + r;
        out[((size_t)(b * Nn + i)) * 128 + hh * 32 + 0  + lrow] = acc0[r];
        out[((size_t)(b * Nn + i)) * 128 + hh * 32 + 16 + lrow] = acc1[r];
    }
}

extern "C" void kernel_launch(void* const* d_in, const int* in_sizes, int n_in,
                              void* d_out, int out_size, void* d_ws, size_t ws_size,
                              hipStream_t stream)
{
    const float* h    = (const float*)d_in[0];
    const int*   adj  = (const int*)d_in[1];
    const float* edge = (const float*)d_in[2];
    const float* W    = (const float*)d_in[3];
    const float* a    = (const float*)d_in[4];
    float* out = (float*)d_out;

    char* ws = (char*)d_ws;
    __bf16* htT   = (__bf16*)(ws);                   //  2,097,152 B
    __bf16* htD   = (__bf16*)(ws + 2097152);         //  2,097,152 B
    float*  s_i   = (float*)(ws + 4194304);          //    131,072 B
    float*  s_j   = (float*)(ws + 4325376);          //    131,072 B
    float*  Dpart = (float*)(ws + 4456448);          // 16,777,216 B
    __bf16* P     = (__bf16*)(ws + 21233664);        // 134,217,728 B  (total ~155 MB)
    float*  rcpD  = s_i;   // s_i dead after K2

    k1_proj  <<<dim3(Nn / 16, Bn),           256, 0, stream>>>(h, W, a, htT, s_i, s_j);
    // PROBE: z doubled (2*ZS) — second half redundant/idempotent
    k2_pexp  <<<dim3(Nn / 512, Bn, 2 * ZS),  256, 0, stream>>>(edge, adj, a, s_i, s_j, P, Dpart);
    k3a_rcp  <<<dim3(Bn * Hh * Nn / 256),    256, 0, stream>>>(Dpart, rcpD);
    k3b_scale<<<dim3(Bn * Hh * HIDn * Nn / 8 / 256), 256, 0, stream>>>(rcpD, htT, htD);
    // PROBE: x octupled — extra blocks redundant/idempotent
    k4_gemm  <<<dim3(8 * (Nn / 64), Bn * Hh), 256, 0, stream>>>(P, htD, out);
}

// Round 9
// 482.060 us; speedup vs baseline: 1.7579x; 1.7579x over previous
//
#include <hip/hip_runtime.h>
#include <hip/hip_bf16.h>
#include <math.h>

#define Bn 4
#define Nn 2048
#define FIN 128
#define Hh 4
#define HIDn 32
#define En 4
#define ZS 128           // i-splits in K2 (16 rows/block -> 2048 blocks, 8 waves/SIMD)
#define RPT (Nn / ZS)    // 16 rows per block
#define BK 128           // K4 K-tile (256 B per row)

typedef __bf16 bf16x8 __attribute__((ext_vector_type(8)));
typedef __bf16 bf16x2 __attribute__((ext_vector_type(2)));
typedef float  f32x4  __attribute__((ext_vector_type(4)));
typedef float  f32x4v __attribute__((ext_vector_type(4)));
typedef int    i32x2v __attribute__((ext_vector_type(2)));

__device__ __forceinline__ f32x4 mfma16(bf16x8 a, bf16x8 b, f32x4 c) {
    return __builtin_amdgcn_mfma_f32_16x16x32_bf16(a, b, c, 0, 0, 0);
}

// K1: ht = h @ W  (B,N,128); emit htT bf16 [b][h][hid][n], s_i/s_j fp32 [b][h][n]
__global__ __launch_bounds__(256) void k1_proj(const float* __restrict__ h,
    const float* __restrict__ W, const float* __restrict__ a,
    __bf16* __restrict__ htT, float* __restrict__ s_i, float* __restrict__ s_j)
{
    __shared__ float hl[16][FIN];
    const int b  = blockIdx.y;
    const int n0 = blockIdx.x * 16;
    const int t  = threadIdx.x;
    for (int k = t; k < 16 * FIN; k += 256) {
        int r = k >> 7, f = k & 127;
        hl[r][f] = h[((size_t)(b * Nn + n0 + r)) * FIN + f];
    }
    __syncthreads();
    const int d   = t & 127;
    const int ng  = t >> 7;
    const int hh  = d >> 5;
    const int hid = d & 31;
    float acc[8];
#pragma unroll
    for (int r = 0; r < 8; r++) acc[r] = 0.f;
    for (int f = 0; f < FIN; f++) {
        float wv = W[f * 128 + d];
#pragma unroll
        for (int r = 0; r < 8; r++) acc[r] = fmaf(hl[ng * 8 + r][f], wv, acc[r]);
    }
    const float ai = a[hh * 68 + hid];
    const float aj = a[hh * 68 + 32 + hid];
#pragma unroll
    for (int r = 0; r < 8; r++) {
        float vi = acc[r] * ai;
        float vj = acc[r] * aj;
#pragma unroll
        for (int m = 16; m >= 1; m >>= 1) {
            vi += __shfl_xor(vi, m, 64);
            vj += __shfl_xor(vj, m, 64);
        }
        if (hid == 0) {
            int n = n0 + ng * 8 + r;
            s_i[(b * Hh + hh) * Nn + n] = vi;
            s_j[(b * Hh + hh) * Nn + n] = vj;
        }
    }
    bf16x8 pack;
#pragma unroll
    for (int r = 0; r < 8; r++) pack[r] = (__bf16)acc[r];
    *(bf16x8*)(htT + ((size_t)((b * Hh + hh) * HIDn + hid)) * Nn + n0 + ng * 8) = pack;
}

// K2: P[b][h][i][j] = adj ? exp(s_i + s_j + edge.a_e) : 0  (bf16, unnormalized)
//     ZS=128 (16 rows/block): 2048 blocks = 8 waves/SIMD for latency hiding.
__global__ __launch_bounds__(256) void k2_pexp(const float* __restrict__ edge,
    const int* __restrict__ adj, const float* __restrict__ a,
    const float* __restrict__ s_i, const float* __restrict__ s_j,
    __bf16* __restrict__ P, float* __restrict__ Dpart)
{
    __shared__ float si_l[4][RPT];
    const int b  = blockIdx.y;
    const int z  = blockIdx.z;
    const int i0 = z * RPT;
    const int t  = threadIdx.x;
    const int j0 = blockIdx.x * 512 + t * 2;
    if (t < 4 * RPT)
        si_l[t >> 4][t & 15] = s_i[(b * Hh + (t >> 4)) * Nn + i0 + (t & 15)];
    float ae[4][4];
#pragma unroll
    for (int hh = 0; hh < 4; hh++)
#pragma unroll
        for (int e = 0; e < 4; e++) ae[hh][e] = a[hh * 68 + 64 + e];
    float sj0[4], sj1[4];
#pragma unroll
    for (int hh = 0; hh < 4; hh++) {
        sj0[hh] = s_j[(b * Hh + hh) * Nn + j0];
        sj1[hh] = s_j[(b * Hh + hh) * Nn + j0 + 1];
    }
    __syncthreads();
    float D0[4] = {0.f, 0.f, 0.f, 0.f};
    float D1[4] = {0.f, 0.f, 0.f, 0.f};
    const float* ep = edge + ((size_t)(b * Nn + i0)) * Nn * En + (size_t)j0 * En;
    const int*   ap = adj  + ((size_t)(b * Nn + i0)) * Nn + j0;
    __bf16*      pp = P    + ((size_t)(b * Hh) * Nn + i0) * Nn + j0;
    const size_t PS = (size_t)Nn * Nn;   // head-plane stride
#pragma unroll 2
    for (int ii = 0; ii < RPT; ii++) {
        const f32x4v e0 = __builtin_nontemporal_load((const f32x4v*)ep);
        const f32x4v e1 = __builtin_nontemporal_load(((const f32x4v*)ep) + 1);
        const i32x2v av = __builtin_nontemporal_load((const i32x2v*)ap);
        ep += (size_t)Nn * En;
        ap += Nn;
#pragma unroll
        for (int hh = 0; hh < 4; hh++) {
            const float base = si_l[hh][ii];
            float d0 = base + sj0[hh];
            float d1 = base + sj1[hh];
            d0 = fmaf(e0[0], ae[hh][0], d0); d0 = fmaf(e0[1], ae[hh][1], d0);
            d0 = fmaf(e0[2], ae[hh][2], d0); d0 = fmaf(e0[3], ae[hh][3], d0);
            d1 = fmaf(e1[0], ae[hh][0], d1); d1 = fmaf(e1[1], ae[hh][1], d1);
            d1 = fmaf(e1[2], ae[hh][2], d1); d1 = fmaf(e1[3], ae[hh][3], d1);
            const float p0 = (av[0] > 0) ? __expf(d0) : 0.f;
            const float p1 = (av[1] > 0) ? __expf(d1) : 0.f;
            D0[hh] += p0;
            D1[hh] += p1;
            bf16x2 pv;
            pv[0] = (__bf16)p0;
            pv[1] = (__bf16)p1;
            *(bf16x2*)(pp + hh * PS) = pv;
        }
        pp += Nn;
    }
#pragma unroll
    for (int hh = 0; hh < 4; hh++) {
        float2 dv;
        dv.x = D0[hh];
        dv.y = D1[hh];
        *(float2*)(Dpart + ((size_t)((b * Hh + hh) * ZS + z)) * Nn + j0) = dv;
    }
}

// K3a: rcpD[bh][j] = 1 / sum_z Dpart[bh][z][j]
//      512 blocks; block = (bh, 64 j's); 4 z-groups of 32 in parallel + LDS combine.
__global__ __launch_bounds__(256) void k3a_rcp(const float* __restrict__ Dpart,
    float* __restrict__ rcpD)
{
    __shared__ float part[4][64];
    const int bh = blockIdx.y;
    const int j0 = blockIdx.x * 64;
    const int t  = threadIdx.x;
    const int jj = t & 63;
    const int zg = t >> 6;
    float S = 0.f;
#pragma unroll 4
    for (int zz = 0; zz < ZS / 4; ++zz)
        S += Dpart[((size_t)(bh * ZS + zg * (ZS / 4) + zz)) * Nn + j0 + jj];
    part[zg][jj] = S;
    __syncthreads();
    if (t < 64) {
        const float tot = part[0][t] + part[1][t] + part[2][t] + part[3][t];
        rcpD[bh * Nn + j0 + t] = (tot > 0.f) ? 1.f / tot : 0.f;
    }
}

// K3b: htD[bh][d][j] = htT[bh][d][j] * rcpD[bh][j]  (bf16x8 vectorized)
__global__ __launch_bounds__(256) void k3b_scale(const float* __restrict__ rcpD,
    const __bf16* __restrict__ htT, __bf16* __restrict__ htD)
{
    const int idx = blockIdx.x * 256 + threadIdx.x;   // [bh][d][n/8]
    const int oct = idx & 255;
    const int d   = (idx >> 8) & 31;
    const int bh  = idx >> 13;
    const int n0  = oct * 8;
    const size_t o = ((size_t)(bh * HIDn + d)) * Nn + n0;
    const bf16x8 v = *(const bf16x8*)(htT + o);
    const float4 r0 = *(const float4*)(rcpD + bh * Nn + n0);
    const float4 r1 = *(const float4*)(rcpD + bh * Nn + n0 + 4);
    bf16x8 w;
    w[0] = (__bf16)((float)v[0] * r0.x);
    w[1] = (__bf16)((float)v[1] * r0.y);
    w[2] = (__bf16)((float)v[2] * r0.z);
    w[3] = (__bf16)((float)v[3] * r0.w);
    w[4] = (__bf16)((float)v[4] * r1.x);
    w[5] = (__bf16)((float)v[5] * r1.y);
    w[6] = (__bf16)((float)v[6] * r1.z);
    w[7] = (__bf16)((float)v[7] * r1.w);
    *(bf16x8*)(htD + o) = w;
}

// K4: out = P @ htD^T per (bh): LDS-staged, XOR-swizzled, double-buffered MFMA.
//     Block: 4 waves, 64 i-rows x 32 d. Reg-staged global->LDS (contiguous 256B
//     row segments), swizzle byte^=(row&7)<<4 kills the 16-way ds_read conflict.
__global__ __launch_bounds__(256) void k4_gemm(const __bf16* __restrict__ P,
    const __bf16* __restrict__ htD, float* __restrict__ out)
{
    __shared__ __align__(16) __bf16 As[2][64 * BK];
    __shared__ __align__(16) __bf16 Bs[2][32 * BK];
    const int bh   = blockIdx.y;
    const int t    = threadIdx.x;
    const int w    = t >> 6;
    const int lane = t & 63;
    const int quad = lane >> 4;
    const int lrow = lane & 15;
    const int lr4  = lane >> 4;     // staging row-in-group
    const int lc   = lane & 15;     // staging chunk (16 B units)
    const int i0   = blockIdx.x * 64;

    const __bf16* Pg = P   + (size_t)bh * Nn * Nn;
    const __bf16* Bg = htD + (size_t)bh * HIDn * Nn;

    bf16x8 rA[4], rB[2];
    f32x4 acc0 = {0.f, 0.f, 0.f, 0.f};
    f32x4 acc1 = {0.f, 0.f, 0.f, 0.f};

    // issue global loads for K-tile kt into registers (coalesced 256B row runs)
    auto ldg = [&](int kt) {
        const int kb = kt * BK;
#pragma unroll
        for (int q = 0; q < 4; ++q) {
            const int ra = w * 16 + q * 4 + lr4;          // local A row 0..63
            rA[q] = *(const bf16x8*)(Pg + (size_t)(i0 + ra) * Nn + kb + lc * 8);
        }
#pragma unroll
        for (int q = 0; q < 2; ++q) {
            const int rb = w * 8 + q * 4 + lr4;           // local B row 0..31
            rB[q] = *(const bf16x8*)(Bg + (size_t)rb * Nn + kb + lc * 8);
        }
    };
    // write staged registers to LDS with XOR swizzle (chunk ^= row&7)
    auto dsw = [&](int bufi) {
#pragma unroll
        for (int q = 0; q < 4; ++q) {
            const int ra = w * 16 + q * 4 + lr4;
            *(bf16x8*)(&As[bufi][ra * BK + ((lc ^ (ra & 7)) * 8)]) = rA[q];
        }
#pragma unroll
        for (int q = 0; q < 2; ++q) {
            const int rb = w * 8 + q * 4 + lr4;
            *(bf16x8*)(&Bs[bufi][rb * BK + ((lc ^ (rb & 7)) * 8)]) = rB[q];
        }
    };

    ldg(0);
    dsw(0);
    const int NT = Nn / BK;   // 16
    const int arow = w * 16 + lrow;
    const int xa = arow & 7;
    const int xb = lrow & 7;
    for (int kt = 0; kt < NT; ++kt) {
        const int cur = kt & 1;
        if (kt + 1 < NT) ldg(kt + 1);    // issue next-tile loads early (T14)
        __syncthreads();                  // cur buffer staged; prev reads done
        const __bf16* Ab = &As[cur][0];
        const __bf16* Bb = &Bs[cur][0];
#pragma unroll
        for (int kk = 0; kk < 4; ++kk) {
            const int c = kk * 4 + quad;
            bf16x8 af = *(const bf16x8*)(Ab + arow * BK + ((c ^ xa) * 8));
            bf16x8 b0 = *(const bf16x8*)(Bb + lrow * BK + ((c ^ xb) * 8));
            bf16x8 b1 = *(const bf16x8*)(Bb + (lrow + 16) * BK + ((c ^ xb) * 8));
            acc0 = mfma16(af, b0, acc0);
            acc1 = mfma16(af, b1, acc1);
        }
        if (kt + 1 < NT) dsw(cur ^ 1);   // write other buffer (safe: barrier above)
    }

    const int b = bh >> 2, hh = bh & 3;
#pragma unroll
    for (int r = 0; r < 4; r++) {
        const int i = i0 + w * 16 + quad * 4 + r;
        out[((size_t)(b * Nn + i)) * 128 + hh * 32 + 0  + lrow] = acc0[r];
        out[((size_t)(b * Nn + i)) * 128 + hh * 32 + 16 + lrow] = acc1[r];
    }
}

extern "C" void kernel_launch(void* const* d_in, const int* in_sizes, int n_in,
                              void* d_out, int out_size, void* d_ws, size_t ws_size,
                              hipStream_t stream)
{
    const float* h    = (const float*)d_in[0];
    const int*   adj  = (const int*)d_in[1];
    const float* edge = (const float*)d_in[2];
    const float* W    = (const float*)d_in[3];
    const float* a    = (const float*)d_in[4];
    float* out = (float*)d_out;

    char* ws = (char*)d_ws;
    __bf16* htT   = (__bf16*)(ws);                   //  2,097,152 B
    __bf16* htD   = (__bf16*)(ws + 2097152);         //  2,097,152 B
    float*  s_i   = (float*)(ws + 4194304);          //    131,072 B
    float*  s_j   = (float*)(ws + 4325376);          //    131,072 B
    float*  Dpart = (float*)(ws + 4456448);          // 16,777,216 B (16x128x2048 fp32)
    __bf16* P     = (__bf16*)(ws + 21233664);        // 134,217,728 B  (total ~155 MB)
    float*  rcpD  = s_i;   // s_i dead after K2

    k1_proj  <<<dim3(Nn / 16, Bn),       256, 0, stream>>>(h, W, a, htT, s_i, s_j);
    k2_pexp  <<<dim3(Nn / 512, Bn, ZS),  256, 0, stream>>>(edge, adj, a, s_i, s_j, P, Dpart);
    k3a_rcp  <<<dim3(Nn / 64, Bn * Hh),  256, 0, stream>>>(Dpart, rcpD);
    k3b_scale<<<dim3(Bn * Hh * HIDn * Nn / 8 / 256), 256, 0, stream>>>(rcpD, htT, htD);
    k4_gemm  <<<dim3(Nn / 64, Bn * Hh),  256, 0, stream>>>(P, htD, out);
}

// Round 12
// 456.051 us; speedup vs baseline: 1.8581x; 1.0570x over previous
//
#include <hip/hip_runtime.h>
#include <hip/hip_bf16.h>
#include <math.h>

#define Bn 4
#define Nn 2048
#define FIN 128
#define Hh 4
#define HIDn 32
#define En 4
#define ZS 32            // i-splits in K2 (r2-measured-best)
#define RPT (Nn / ZS)    // 64 rows per block
#define BK 128           // K4 K-tile

typedef __bf16 bf16x8 __attribute__((ext_vector_type(8)));
typedef __bf16 bf16x2 __attribute__((ext_vector_type(2)));
typedef float  f32x4  __attribute__((ext_vector_type(4)));
typedef float  f32x4v __attribute__((ext_vector_type(4)));
typedef int    i32x2v __attribute__((ext_vector_type(2)));

__device__ __forceinline__ f32x4 mfma16(bf16x8 a, bf16x8 b, f32x4 c) {
    return __builtin_amdgcn_mfma_f32_16x16x32_bf16(a, b, c, 0, 0, 0);
}

// K1: ht = h @ W  (B,N,128); emit htT bf16 [b][h][hid][n], s_i/s_j fp32 [b][h][n]
//     (r2-measured-best, unchanged)
__global__ __launch_bounds__(256) void k1_proj(const float* __restrict__ h,
    const float* __restrict__ W, const float* __restrict__ a,
    __bf16* __restrict__ htT, float* __restrict__ s_i, float* __restrict__ s_j)
{
    __shared__ float hl[16][FIN];
    const int b  = blockIdx.y;
    const int n0 = blockIdx.x * 16;
    const int t  = threadIdx.x;
    for (int k = t; k < 16 * FIN; k += 256) {
        int r = k >> 7, f = k & 127;
        hl[r][f] = h[((size_t)(b * Nn + n0 + r)) * FIN + f];
    }
    __syncthreads();
    const int d   = t & 127;
    const int ng  = t >> 7;
    const int hh  = d >> 5;
    const int hid = d & 31;
    float acc[8];
#pragma unroll
    for (int r = 0; r < 8; r++) acc[r] = 0.f;
    for (int f = 0; f < FIN; f++) {
        float wv = W[f * 128 + d];
#pragma unroll
        for (int r = 0; r < 8; r++) acc[r] = fmaf(hl[ng * 8 + r][f], wv, acc[r]);
    }
    const float ai = a[hh * 68 + hid];
    const float aj = a[hh * 68 + 32 + hid];
#pragma unroll
    for (int r = 0; r < 8; r++) {
        float vi = acc[r] * ai;
        float vj = acc[r] * aj;
#pragma unroll
        for (int m = 16; m >= 1; m >>= 1) {
            vi += __shfl_xor(vi, m, 64);
            vj += __shfl_xor(vj, m, 64);
        }
        if (hid == 0) {
            int n = n0 + ng * 8 + r;
            s_i[(b * Hh + hh) * Nn + n] = vi;
            s_j[(b * Hh + hh) * Nn + n] = vj;
        }
    }
    bf16x8 pack;
#pragma unroll
    for (int r = 0; r < 8; r++) pack[r] = (__bf16)acc[r];
    *(bf16x8*)(htT + ((size_t)((b * Hh + hh) * HIDn + hid)) * Nn + n0 + ng * 8) = pack;
}

// K2: P[b][h][i][j] = adj ? exp(s_i + s_j + edge.a_e) : 0  (bf16, unnormalized)
//     Dpart[b][h][z][j] = partial column sums (r2-measured-best, unchanged)
__global__ __launch_bounds__(256) void k2_pexp(const float* __restrict__ edge,
    const int* __restrict__ adj, const float* __restrict__ a,
    const float* __restrict__ s_i, const float* __restrict__ s_j,
    __bf16* __restrict__ P, float* __restrict__ Dpart)
{
    __shared__ float si_l[4][RPT];
    const int b  = blockIdx.y;
    const int z  = blockIdx.z;
    const int i0 = z * RPT;
    const int t  = threadIdx.x;
    const int j0 = blockIdx.x * 512 + t * 2;
    si_l[t >> 6][t & 63] = s_i[(b * Hh + (t >> 6)) * Nn + i0 + (t & 63)];
    float ae[4][4];
#pragma unroll
    for (int hh = 0; hh < 4; hh++)
#pragma unroll
        for (int e = 0; e < 4; e++) ae[hh][e] = a[hh * 68 + 64 + e];
    float sj0[4], sj1[4];
#pragma unroll
    for (int hh = 0; hh < 4; hh++) {
        sj0[hh] = s_j[(b * Hh + hh) * Nn + j0];
        sj1[hh] = s_j[(b * Hh + hh) * Nn + j0 + 1];
    }
    __syncthreads();
    float D0[4] = {0.f, 0.f, 0.f, 0.f};
    float D1[4] = {0.f, 0.f, 0.f, 0.f};
    const float* ep = edge + ((size_t)(b * Nn + i0)) * Nn * En + (size_t)j0 * En;
    const int*   ap = adj  + ((size_t)(b * Nn + i0)) * Nn + j0;
    __bf16*      pp = P    + ((size_t)(b * Hh) * Nn + i0) * Nn + j0;
    const size_t PS = (size_t)Nn * Nn;   // head-plane stride
#pragma unroll 2
    for (int ii = 0; ii < RPT; ii++) {
        const f32x4v e0 = __builtin_nontemporal_load((const f32x4v*)ep);
        const f32x4v e1 = __builtin_nontemporal_load(((const f32x4v*)ep) + 1);
        const i32x2v av = __builtin_nontemporal_load((const i32x2v*)ap);
        ep += (size_t)Nn * En;
        ap += Nn;
#pragma unroll
        for (int hh = 0; hh < 4; hh++) {
            const float base = si_l[hh][ii];
            float d0 = base + sj0[hh];
            float d1 = base + sj1[hh];
            d0 = fmaf(e0[0], ae[hh][0], d0); d0 = fmaf(e0[1], ae[hh][1], d0);
            d0 = fmaf(e0[2], ae[hh][2], d0); d0 = fmaf(e0[3], ae[hh][3], d0);
            d1 = fmaf(e1[0], ae[hh][0], d1); d1 = fmaf(e1[1], ae[hh][1], d1);
            d1 = fmaf(e1[2], ae[hh][2], d1); d1 = fmaf(e1[3], ae[hh][3], d1);
            const float p0 = (av[0] > 0) ? __expf(d0) : 0.f;
            const float p1 = (av[1] > 0) ? __expf(d1) : 0.f;
            D0[hh] += p0;
            D1[hh] += p1;
            bf16x2 pv;
            pv[0] = (__bf16)p0;
            pv[1] = (__bf16)p1;
            *(bf16x2*)(pp + hh * PS) = pv;
        }
        pp += Nn;
    }
#pragma unroll
    for (int hh = 0; hh < 4; hh++) {
        float2 dv;
        dv.x = D0[hh];
        dv.y = D1[hh];
        *(float2*)(Dpart + ((size_t)((b * Hh + hh) * ZS + z)) * Nn + j0) = dv;
    }
}

// K3 (FUSED K3a+K3b): per block = (bh, 64 j's):
//   phase 1: D[j] = sum_z Dpart[bh][z][j] (4 z-groups x 64 j, LDS combine) -> rcp LDS
//   phase 2: htD[bh][d][j] = htT[bh][d][j] * rcp[j]  (32 d x 8 j per thread, bf16x8)
// 512 blocks (2/CU), no rcpD global buffer, one launch instead of two.
__global__ __launch_bounds__(256) void k3_fused(const float* __restrict__ Dpart,
    const __bf16* __restrict__ htT, __bf16* __restrict__ htD)
{
    __shared__ float part[4][64];
    __shared__ float rcp[64];
    const int bh = blockIdx.y;
    const int j0 = blockIdx.x * 64;
    const int t  = threadIdx.x;
    const int jj = t & 63;
    const int zg = t >> 6;
    float S = 0.f;
#pragma unroll
    for (int zz = 0; zz < ZS / 4; ++zz)
        S += Dpart[((size_t)(bh * ZS + zg * (ZS / 4) + zz)) * Nn + j0 + jj];
    part[zg][jj] = S;
    __syncthreads();
    if (t < 64) {
        const float tot = part[0][t] + part[1][t] + part[2][t] + part[3][t];
        rcp[t] = (tot > 0.f) ? 1.f / tot : 0.f;
    }
    __syncthreads();
    const int d  = t >> 3;            // 0..31
    const int jo = (t & 7) * 8;       // 0..56
    const size_t o = ((size_t)(bh * HIDn + d)) * Nn + j0 + jo;
    const bf16x8 v = *(const bf16x8*)(htT + o);
    bf16x8 w;
#pragma unroll
    for (int k = 0; k < 8; k++) w[k] = (__bf16)((float)v[k] * rcp[jo + k]);
    *(bf16x8*)(htD + o) = w;
}

// K4: out = P @ htD^T per (bh): LDS-staged, XOR-swizzled, double-buffered MFMA.
//     (r9 version, measured ~= direct K4; kept for better cold-P pipelining)
__global__ __launch_bounds__(256) void k4_gemm(const __bf16* __restrict__ P,
    const __bf16* __restrict__ htD, float* __restrict__ out)
{
    __shared__ __align__(16) __bf16 As[2][64 * BK];
    __shared__ __align__(16) __bf16 Bs[2][32 * BK];
    const int bh   = blockIdx.y;
    const int t    = threadIdx.x;
    const int w    = t >> 6;
    const int lane = t & 63;
    const int quad = lane >> 4;
    const int lrow = lane & 15;
    const int lr4  = lane >> 4;
    const int lc   = lane & 15;
    const int i0   = blockIdx.x * 64;

    const __bf16* Pg = P   + (size_t)bh * Nn * Nn;
    const __bf16* Bg = htD + (size_t)bh * HIDn * Nn;

    bf16x8 rA[4], rB[2];
    f32x4 acc0 = {0.f, 0.f, 0.f, 0.f};
    f32x4 acc1 = {0.f, 0.f, 0.f, 0.f};

    auto ldg = [&](int kt) {
        const int kb = kt * BK;
#pragma unroll
        for (int q = 0; q < 4; ++q) {
            const int ra = w * 16 + q * 4 + lr4;
            rA[q] = *(const bf16x8*)(Pg + (size_t)(i0 + ra) * Nn + kb + lc * 8);
        }
#pragma unroll
        for (int q = 0; q < 2; ++q) {
            const int rb = w * 8 + q * 4 + lr4;
            rB[q] = *(const bf16x8*)(Bg + (size_t)rb * Nn + kb + lc * 8);
        }
    };
    auto dsw = [&](int bufi) {
#pragma unroll
        for (int q = 0; q < 4; ++q) {
            const int ra = w * 16 + q * 4 + lr4;
            *(bf16x8*)(&As[bufi][ra * BK + ((lc ^ (ra & 7)) * 8)]) = rA[q];
        }
#pragma unroll
        for (int q = 0; q < 2; ++q) {
            const int rb = w * 8 + q * 4 + lr4;
            *(bf16x8*)(&Bs[bufi][rb * BK + ((lc ^ (rb & 7)) * 8)]) = rB[q];
        }
    };

    ldg(0);
    dsw(0);
    const int NT = Nn / BK;   // 16
    const int arow = w * 16 + lrow;
    const int xa = arow & 7;
    const int xb = lrow & 7;
    for (int kt = 0; kt < NT; ++kt) {
        const int cur = kt & 1;
        if (kt + 1 < NT) ldg(kt + 1);    // issue next-tile loads early (T14)
        __syncthreads();                  // cur staged; prev reads done
        const __bf16* Ab = &As[cur][0];
        const __bf16* Bb = &Bs[cur][0];
#pragma unroll
        for (int kk = 0; kk < 4; ++kk) {
            const int c = kk * 4 + quad;
            bf16x8 af = *(const bf16x8*)(Ab + arow * BK + ((c ^ xa) * 8));
            bf16x8 b0 = *(const bf16x8*)(Bb + lrow * BK + ((c ^ xb) * 8));
            bf16x8 b1 = *(const bf16x8*)(Bb + (lrow + 16) * BK + ((c ^ xb) * 8));
            acc0 = mfma16(af, b0, acc0);
            acc1 = mfma16(af, b1, acc1);
        }
        if (kt + 1 < NT) dsw(cur ^ 1);
    }

    const int b = bh >> 2, hh = bh & 3;
#pragma unroll
    for (int r = 0; r < 4; r++) {
        const int i = i0 + w * 16 + quad * 4 + r;
        out[((size_t)(b * Nn + i)) * 128 + hh * 32 + 0  + lrow] = acc0[r];
        out[((size_t)(b * Nn + i)) * 128 + hh * 32 + 16 + lrow] = acc1[r];
    }
}

extern "C" void kernel_launch(void* const* d_in, const int* in_sizes, int n_in,
                              void* d_out, int out_size, void* d_ws, size_t ws_size,
                              hipStream_t stream)
{
    const float* h    = (const float*)d_in[0];
    const int*   adj  = (const int*)d_in[1];
    const float* edge = (const float*)d_in[2];
    const float* W    = (const float*)d_in[3];
    const float* a    = (const float*)d_in[4];
    float* out = (float*)d_out;

    char* ws = (char*)d_ws;
    __bf16* htT   = (__bf16*)(ws);                   //  2,097,152 B
    __bf16* htD   = (__bf16*)(ws + 2097152);         //  2,097,152 B
    float*  s_i   = (float*)(ws + 4194304);          //    131,072 B
    float*  s_j   = (float*)(ws + 4325376);          //    131,072 B
    float*  Dpart = (float*)(ws + 4456448);          //  4,194,304 B (ZS=32)
    __bf16* P     = (__bf16*)(ws + 8650752);         // 134,217,728 B (total ~143 MB)

    k1_proj <<<dim3(Nn / 16, Bn),      256, 0, stream>>>(h, W, a, htT, s_i, s_j);
    k2_pexp <<<dim3(Nn / 512, Bn, ZS), 256, 0, stream>>>(edge, adj, a, s_i, s_j, P, Dpart);
    k3_fused<<<dim3(Nn / 64, Bn * Hh), 256, 0, stream>>>(Dpart, htT, htD);
    k4_gemm <<<dim3(Nn / 64, Bn * Hh), 256, 0, stream>>>(P, htD, out);
}